// Round 18
// baseline (243.517 us; speedup 1.0000x reference)
//
#include <hip/hip_runtime.h>
#include <math.h>

#define NB   8
#define LLEN 2048
#define HDIM 1024
#define LNEPS 1e-5f

#define BM 128               // 128^2 tiles for fp8 kernels (2 blocks/CU)
#define BK 64                // bf16 K-tile (elems); fp8 K-tile = 128 (bytes)
#define NT_K (HDIM / BK)     // 16 bf16 K-tiles
#define NT_K8 (HDIM / 128)   // 8 fp8 K-tiles
#define NTHR 256             // 4 waves (128^2 kernels)
#define TB 16384             // 128^2 tile bytes: 128 rows x 128 B

#define BM2 256              // 256^2 tile for bf16 FF (1 block/CU, 8 waves)
#define NTHR2 512
#define SLOT2 (BM2 * BK)     // 32 KiB per 256^2 operand slot

typedef __attribute__((ext_vector_type(8))) short short8;
typedef __attribute__((ext_vector_type(4))) unsigned short ushort4v;
typedef __attribute__((ext_vector_type(4))) float f32x4;
typedef __attribute__((ext_vector_type(4))) int int4v;
typedef __attribute__((ext_vector_type(8))) int int8v;
typedef __attribute__((ext_vector_type(8))) unsigned char uchar8;

typedef __attribute__((address_space(3))) void lds_void;
typedef const __attribute__((address_space(1))) void glob_void;

__device__ __forceinline__ unsigned short f2bf(float f) {
    union { float f; unsigned u; } v; v.f = f;
    unsigned r = v.u + 0x7FFFu + ((v.u >> 16) & 1u);
    return (unsigned short)(r >> 16);
}
__device__ __forceinline__ float bf2f(unsigned short h) {
    union { unsigned u; float f; } v; v.u = ((unsigned)h) << 16;
    return v.f;
}

// OCP e4m3fn encode, RNE (HW-verified rounds 8-16). Fallback path.
__device__ __forceinline__ unsigned char f2fp8(float x) {
    union { float f; unsigned u; } v; v.f = x;
    unsigned s = (v.u >> 24) & 0x80u;
    float a = fabsf(x);
    if (!(a < 448.f)) return (unsigned char)(s | 0x7E);
    int e = (int)((v.u >> 23) & 0xFF) - 127;
    if (e < -6) e = -6;
    float q = rintf(ldexpf(a, 3 - e));
    if (q >= 16.f) { q *= 0.5f; e += 1; }
    int qi = (int)q;
    unsigned byte = (qi < 8) ? (unsigned)qi
                             : (((unsigned)(e + 7) << 3) | (unsigned)(qi - 8));
    return (unsigned char)(s | byte);
}
// e4m3fn decode (cold path, 4/thread in ln1)
__device__ __forceinline__ float fp8d(unsigned char b) {
    int e = (b >> 3) & 15, m = b & 7;
    float v = e ? ldexpf((float)(8 + m), e - 10) : ldexpf((float)m, -9);
    return (b & 0x80) ? -v : v;
}

// Pack 4 f32 -> 4 fp8 bytes (HW v_cvt_pk_fp8_f32 when available).
__device__ __forceinline__ unsigned pack4_fp8(float a, float b, float c, float d) {
#if __has_builtin(__builtin_amdgcn_cvt_pk_fp8_f32)
    int r = __builtin_amdgcn_cvt_pk_fp8_f32(a, b, 0, false);
    r = __builtin_amdgcn_cvt_pk_fp8_f32(c, d, r, true);
    return (unsigned)r;
#else
    return (unsigned)f2fp8(a) | ((unsigned)f2fp8(b) << 8)
         | ((unsigned)f2fp8(c) << 16) | ((unsigned)f2fp8(d) << 24);
#endif
}

__device__ __forceinline__ void wg_barrier() {
    asm volatile("" ::: "memory");
    __builtin_amdgcn_s_barrier();
    asm volatile("" ::: "memory");
}

// ================= 128^2 pipelines (fp8 qk/proj + wqk splitk) =================
// XOR swizzle byte(r,cb) = r*128 + (cb ^ ((r&7)<<4)); pre-applied to the
// per-lane GLOBAL source (rule 21), LDS dest linear.
__device__ __forceinline__ void stage128_bf16(
    const unsigned short* __restrict__ src, int R0, int kcol0,
    unsigned short* ldsDst, int w, int l)
{
    const int rsub = l >> 3;
    const int ce = 8 * ((l & 7) ^ rsub);
    #pragma unroll
    for (int s = 0; s < 4; ++s) {
        const int r = s*32 + w*8 + rsub;
        __builtin_amdgcn_global_load_lds(
            (glob_void*)(src + (size_t)(R0 + r) * HDIM + kcol0 + ce),
            (lds_void*)(ldsDst + s*2048 + w*512), 16, 0, 0);
    }
}

__device__ __forceinline__ void stage128_fp8(
    const unsigned char* __restrict__ src, int R0, int kcol0,
    unsigned char* ldsDst, int w, int l)
{
    const int rsub = l >> 3;
    const int cb = ((l & 7) ^ rsub) << 4;
    #pragma unroll
    for (int s = 0; s < 4; ++s) {
        const int r = s*32 + w*8 + rsub;
        __builtin_amdgcn_global_load_lds(
            (glob_void*)(src + (size_t)(R0 + r) * HDIM + kcol0 + cb),
            (lds_void*)(ldsDst + s*4096 + w*1024), 16, 0, 0);
    }
}

__device__ __forceinline__ void pipe128_bf16(
    const unsigned short* __restrict__ srcA,
    const unsigned short* __restrict__ srcB,
    int rowBase, int colBase, int k0, int nt,
    unsigned short* lds, f32x4 (&acc)[4][4])
{
    const int t = threadIdx.x, w = t >> 6, l = t & 63;
    const int wr = w >> 1, wc = w & 1;
    const int lr = l & 15;
    const int sw = (l & 7) << 4;
    const int aRB = (wr*64 + lr) * 128;
    const int bRB = (wc*64 + lr) * 128;
    const int c0 = ((l >> 4) * 16) ^ sw;
    const int c1 = (64 + ((l >> 4) * 16)) ^ sw;

    unsigned short* sA[2] = { lds,          lds + 2*(TB/2) };
    unsigned short* sB[2] = { lds + TB/2,   lds + 3*(TB/2) };

    stage128_bf16(srcA, rowBase, k0,      sA[0], w, l);
    stage128_bf16(srcB, colBase, k0,      sB[0], w, l);
    stage128_bf16(srcA, rowBase, k0 + BK, sA[1], w, l);
    stage128_bf16(srcB, colBase, k0 + BK, sB[1], w, l);
    asm volatile("s_waitcnt vmcnt(8)" ::: "memory");
    wg_barrier();

    for (int kt = 0; kt < nt; ++kt) {
        const char* bufA = (const char*)sA[kt & 1];
        const char* bufB = (const char*)sB[kt & 1];
        #pragma unroll
        for (int kk = 0; kk < 2; ++kk) {
            const int cc = kk ? c1 : c0;
            short8 af[4], bfr[4];
            #pragma unroll
            for (int mi = 0; mi < 4; ++mi)
                af[mi] = *(const short8*)(bufA + aRB + mi*2048 + cc);
            #pragma unroll
            for (int ni = 0; ni < 4; ++ni)
                bfr[ni] = *(const short8*)(bufB + bRB + ni*2048 + cc);
            #pragma unroll
            for (int mi = 0; mi < 4; ++mi)
                #pragma unroll
                for (int ni = 0; ni < 4; ++ni)
                    acc[mi][ni] = __builtin_amdgcn_mfma_f32_16x16x32_bf16(
                        af[mi], bfr[ni], acc[mi][ni], 0, 0, 0);
        }
        if (kt == nt - 1) break;
        wg_barrier();
        if (kt + 2 < nt) {
            stage128_bf16(srcA, rowBase, k0 + (kt+2)*BK, sA[kt&1], w, l);
            stage128_bf16(srcB, colBase, k0 + (kt+2)*BK, sB[kt&1], w, l);
            asm volatile("s_waitcnt vmcnt(8)" ::: "memory");
        } else {
            asm volatile("s_waitcnt vmcnt(0)" ::: "memory");
        }
        wg_barrier();
    }
}

__device__ __forceinline__ void pipe128_fp8(
    const unsigned char* __restrict__ srcA,
    const unsigned char* __restrict__ srcB,
    int rowBase, int colBase,
    unsigned char* lds, f32x4 (&acc)[4][4],
    unsigned sa, unsigned sb)
{
    const int t = threadIdx.x, w = t >> 6, l = t & 63;
    const int wr = w >> 1, wc = w & 1;
    const int lr = l & 15;
    const int sw = (l & 7) << 4;
    const int aRB = (wr*64 + lr) * 128;
    const int bRB = (wc*64 + lr) * 128;
    const int g0 = (l >> 4) * 32;
    const int cc0 = g0 ^ sw;
    const int cc1 = (g0 + 16) ^ sw;

    unsigned char* sA[2] = { lds,        lds + 2*TB };
    unsigned char* sB[2] = { lds + TB,   lds + 3*TB };

    stage128_fp8(srcA, rowBase, 0,   sA[0], w, l);
    stage128_fp8(srcB, colBase, 0,   sB[0], w, l);
    stage128_fp8(srcA, rowBase, 128, sA[1], w, l);
    stage128_fp8(srcB, colBase, 128, sB[1], w, l);
    asm volatile("s_waitcnt vmcnt(8)" ::: "memory");
    wg_barrier();

    for (int kt = 0; kt < NT_K8; ++kt) {
        const char* bufA = (const char*)sA[kt & 1];
        const char* bufB = (const char*)sB[kt & 1];
        int8v b8[4];
        #pragma unroll
        for (int ni = 0; ni < 4; ++ni)
            b8[ni] = __builtin_shufflevector(
                *(const int4v*)(bufB + bRB + ni*2048 + cc0),
                *(const int4v*)(bufB + bRB + ni*2048 + cc1),
                0, 1, 2, 3, 4, 5, 6, 7);
        #pragma unroll
        for (int mi = 0; mi < 4; ++mi) {
            int8v a8 = __builtin_shufflevector(
                *(const int4v*)(bufA + aRB + mi*2048 + cc0),
                *(const int4v*)(bufA + aRB + mi*2048 + cc1),
                0, 1, 2, 3, 4, 5, 6, 7);
            #pragma unroll
            for (int ni = 0; ni < 4; ++ni)
                acc[mi][ni] = __builtin_amdgcn_mfma_scale_f32_16x16x128_f8f6f4(
                    a8, b8[ni], acc[mi][ni], 0, 0, 0, sa, 0, sb);
        }
        if (kt == NT_K8 - 1) break;
        wg_barrier();
        if (kt + 2 < NT_K8) {
            stage128_fp8(srcA, rowBase, (kt+2)*128, sA[kt&1], w, l);
            stage128_fp8(srcB, colBase, (kt+2)*128, sB[kt&1], w, l);
            asm volatile("s_waitcnt vmcnt(8)" ::: "memory");
        } else {
            asm volatile("s_waitcnt vmcnt(0)" ::: "memory");
        }
        wg_barrier();
    }
}

// ================= 256^2 bf16 pipeline (FF only; round-14/16 proven) =================
__device__ __forceinline__ void stage256_bf16(
    const unsigned short* __restrict__ src, int R0, int kcol0,
    unsigned short* ldsDst, int w, int lane)
{
    const int rsub = lane >> 3;
    const int csw  = 8 * ((lane & 7) ^ rsub);
    #pragma unroll
    for (int s = 0; s < 4; ++s) {
        const int r = (s*8 + w)*8 + rsub;
        __builtin_amdgcn_global_load_lds(
            (glob_void*)(src + (size_t)(R0 + r) * HDIM + kcol0 + csw),
            (lds_void*)(ldsDst + (s*8 + w)*512), 16, 0, 0);
    }
}

__device__ __forceinline__ void pipe256_bf16(
    const unsigned short* __restrict__ srcA,
    const unsigned short* __restrict__ srcB,
    int rowBase, int colBase,
    unsigned short* lds, f32x4 (&acc)[8][4])
{
    const int t = threadIdx.x, w = t >> 6, l = t & 63;
    const int wr = w >> 2, wc = w & 3;
    const int lr = l & 15;
    const int sw = (l & 7) << 4;
    const int aRB = (wr*128 + lr) * 128;
    const int bRB = (wc*64  + lr) * 128;
    const int c0 = ((l >> 4) * 16) ^ sw;
    const int c1 = (64 + ((l >> 4) * 16)) ^ sw;

    unsigned short* sA[2] = { lds,            lds + 2*SLOT2 };
    unsigned short* sB[2] = { lds + SLOT2,    lds + 3*SLOT2 };

    stage256_bf16(srcA, rowBase, 0,  sA[0], w, l);
    stage256_bf16(srcB, colBase, 0,  sB[0], w, l);
    stage256_bf16(srcA, rowBase, BK, sA[1], w, l);
    stage256_bf16(srcB, colBase, BK, sB[1], w, l);
    asm volatile("s_waitcnt vmcnt(8)" ::: "memory");
    wg_barrier();

    for (int kt = 0; kt < NT_K; ++kt) {
        const char* bufA = (const char*)sA[kt & 1];
        const char* bufB = (const char*)sB[kt & 1];
        #pragma unroll
        for (int kk = 0; kk < 2; ++kk) {
            const int cc = kk ? c1 : c0;
            short8 af[8], bfr[4];
            #pragma unroll
            for (int mi = 0; mi < 8; ++mi)
                af[mi] = *(const short8*)(bufA + aRB + mi*2048 + cc);
            #pragma unroll
            for (int ni = 0; ni < 4; ++ni)
                bfr[ni] = *(const short8*)(bufB + bRB + ni*2048 + cc);
            #pragma unroll
            for (int mi = 0; mi < 8; ++mi)
                #pragma unroll
                for (int ni = 0; ni < 4; ++ni)
                    acc[mi][ni] = __builtin_amdgcn_mfma_f32_16x16x32_bf16(
                        af[mi], bfr[ni], acc[mi][ni], 0, 0, 0);
        }
        if (kt == NT_K - 1) break;
        wg_barrier();
        if (kt + 2 < NT_K) {
            stage256_bf16(srcA, rowBase, (kt+2)*BK, sA[kt&1], w, l);
            stage256_bf16(srcB, colBase, (kt+2)*BK, sB[kt&1], w, l);
            asm volatile("s_waitcnt vmcnt(8)" ::: "memory");
        } else {
            asm volatile("s_waitcnt vmcnt(0)" ::: "memory");
        }
        wg_barrier();
    }
}

// ---- FF GEMM (bf16, 256^2) + fused residual: Y = bf16(A@Bt^T + bias + h1) ----
__global__ __launch_bounds__(NTHR2, 2) void gemm_ff(
    const unsigned short* __restrict__ A,
    const unsigned short* __restrict__ Bt,
    const float* __restrict__ bias,
    const unsigned short* __restrict__ h1res,
    unsigned short* __restrict__ Y, int gx)
{
    __shared__ __align__(16) unsigned short lds[4 * SLOT2];   // 128 KiB
    const int nwg = gridDim.x, bid = blockIdx.x;
    const int swz = (bid & 7) * (nwg >> 3) + (bid >> 3);
    const int bx = swz % gx, by = swz / gx;
    const int rowBase = by * BM2, colBase = bx * BM2;

    f32x4 acc[8][4] = {};
    pipe256_bf16(A, Bt, rowBase, colBase, lds, acc);

    const int t = threadIdx.x, w = t >> 6, l = t & 63;
    const int wr = w >> 2, wc = w & 3;
    const int lr = l & 15;

    #pragma unroll
    for (int ni = 0; ni < 4; ++ni) {
        const int col = colBase + wc*64 + ni*16 + lr;
        const float bv = bias[col];
        #pragma unroll
        for (int mi = 0; mi < 8; ++mi) {
            const int row0 = rowBase + wr*128 + mi*16 + (l >> 4) * 4;
            #pragma unroll
            for (int j = 0; j < 4; ++j) {
                const size_t idx = (size_t)(row0 + j) * HDIM + col;
                Y[idx] = f2bf(acc[mi][ni][j] + bv + bf2f(h1res[idx]));
            }
        }
    }
}

// ---- Wqk split-K (128^2): 64 tiles x 4 K-slices; f32 partial slabs ----
__global__ __launch_bounds__(NTHR) void gemm_wqk_splitk(
    const unsigned short* __restrict__ Wkb,
    const unsigned short* __restrict__ Wqb,
    float* __restrict__ slabs)
{
    __shared__ __align__(16) unsigned short lds[2 * TB];
    const int bid = blockIdx.x;      // 256
    const int kz = bid & 3, tile = bid >> 2;
    const int rowBase = (tile >> 3) * BM, colBase = (tile & 7) * BM;

    f32x4 acc[4][4] = {};
    pipe128_bf16(Wkb, Wqb, rowBase, colBase, kz * (HDIM/4), NT_K/4, lds, acc);

    float* out = slabs + (size_t)kz * HDIM * HDIM;
    const int t = threadIdx.x, w = t >> 6, l = t & 63;
    const int wr = w >> 1, wc = w & 1;
    const int lr = l & 15;

    #pragma unroll
    for (int ni = 0; ni < 4; ++ni) {
        const int col = colBase + wc*64 + ni*16 + lr;
        #pragma unroll
        for (int mi = 0; mi < 4; ++mi) {
            const int row0 = rowBase + wr*64 + mi*16 + (l >> 4) * 4;
            #pragma unroll
            for (int j = 0; j < 4; ++j)
                out[(size_t)(row0 + j) * HDIM + col] = acc[mi][ni][j];
        }
    }
}

// ---- sum 4 slabs, scale x64, write fp8 ----
__global__ __launch_bounds__(256) void wqk_reduce_cast(
    const float* __restrict__ slabs, unsigned char* __restrict__ out8)
{
    const size_t WEl = (size_t)HDIM * HDIM;
    const size_t i = ((size_t)blockIdx.x * 256 + threadIdx.x) * 4;
    float4 a = *reinterpret_cast<const float4*>(slabs + i);
    float4 b = *reinterpret_cast<const float4*>(slabs + WEl + i);
    float4 c = *reinterpret_cast<const float4*>(slabs + 2*WEl + i);
    float4 d = *reinterpret_cast<const float4*>(slabs + 3*WEl + i);
    unsigned wd = pack4_fp8(64.f*(a.x+b.x+c.x+d.x), 64.f*(a.y+b.y+c.y+d.y),
                            64.f*(a.z+b.z+c.z+d.z), 64.f*(a.w+b.w+c.w+d.w));
    *reinterpret_cast<unsigned*>(out8 + i) = wd;
}

// ---- fp8 fused proj (128^2): [Xq8 | V8] = fp8( al * (Xb8 @ W8^T + bias) ) ----
__global__ __launch_bounds__(NTHR) void gemm_proj_fp8(
    const unsigned char* __restrict__ A,
    const unsigned char* __restrict__ Bt,
    const float* __restrict__ bias0, const float* __restrict__ bias1,
    unsigned char* __restrict__ C0, unsigned char* __restrict__ C1,
    float al0, float al1, unsigned sb0, unsigned sb1, int gx)
{
    __shared__ __align__(16) unsigned char lds8[4 * TB];
    const int nwg = gridDim.x, bid = blockIdx.x;
    const int swz = (bid & 7) * (nwg >> 3) + (bid >> 3);
    const int bx = swz % gx, by = swz / gx;
    const int rowBase = by * BM, colBase = bx * BM;

    const int mat = colBase >> 10;

    f32x4 acc[4][4] = {};
    pipe128_fp8(A, Bt, rowBase, colBase, lds8, acc,
                0x7F7F7F7Fu, mat ? sb1 : sb0);

    const int t = threadIdx.x, w = t >> 6, l = t & 63;
    const int wr = w >> 1, wc = w & 1;
    const int lr = l & 15;

    unsigned char* Cm  = mat ? C1 : C0;
    const float* bm    = mat ? bias1 : bias0;
    const float am     = mat ? al1 : al0;
    const int lcb = colBase & (HDIM - 1);

    #pragma unroll
    for (int ni = 0; ni < 4; ++ni) {
        const int col = lcb + wc*64 + ni*16 + lr;
        const float bv = bm[col];
        #pragma unroll
        for (int mi = 0; mi < 4; ++mi) {
            const int row0 = rowBase + wr*64 + mi*16 + (l >> 4) * 4;
            const unsigned wd = pack4_fp8(
                am * (acc[mi][ni][0] + bv), am * (acc[mi][ni][1] + bv),
                am * (acc[mi][ni][2] + bv), am * (acc[mi][ni][3] + bv));
            #pragma unroll
            for (int j = 0; j < 4; ++j)
                Cm[(size_t)(row0 + j) * HDIM + col] = (unsigned char)(wd >> (8*j));
        }
    }
}

// ---- fp8 qk (128^2), batch-per-XCD grid: bid&7 = batch ----
__global__ __launch_bounds__(NTHR) void qk_colsum_diag_fp8(
    const unsigned char* __restrict__ Xq8,
    const unsigned char* __restrict__ Xb8,
    const float* __restrict__ uvec,
    float* __restrict__ colsum, float* __restrict__ diagv)
{
    __shared__ __align__(16) unsigned char lds8[4 * TB];
    const int bid = blockIdx.x;          // 2048
    const int n = bid & 7;
    const int rem = bid >> 3;            // 0..255
    const int rowBase = (rem & 15) * BM;
    const int colBase = (rem >> 4) * BM;
    const unsigned char* An = Xq8 + (size_t)n * LLEN * HDIM;
    const unsigned char* Bn = Xb8 + (size_t)n * LLEN * HDIM;

    f32x4 acc[4][4] = {};
    pipe128_fp8(An, Bn, rowBase, colBase, lds8, acc,
                0x75757575u, 0x7F7F7F7Fu);

    const int t = threadIdx.x, w = t >> 6, l = t & 63;
    const int wr = w >> 1, wc = w & 1;
    const int lr = l & 15;

    float ur[4][4];
    #pragma unroll
    for (int mi = 0; mi < 4; ++mi)
        #pragma unroll
        for (int j = 0; j < 4; ++j)
            ur[mi][j] = uvec[(size_t)n * LLEN + rowBase + wr*64 + mi*16 + (l>>4)*4 + j];

    #pragma unroll
    for (int ni = 0; ni < 4; ++ni) {
        float s = 0.f;
        #pragma unroll
        for (int mi = 0; mi < 4; ++mi)
            #pragma unroll
            for (int j = 0; j < 4; ++j)
                s += __expf(acc[mi][ni][j] + ur[mi][j]);
        s += __shfl_xor(s, 16);
        s += __shfl_xor(s, 32);
        if (l < 16)
            atomicAdd(&colsum[(size_t)n * LLEN + colBase + wc*64 + ni*16 + l], s);
    }

    if (rowBase == colBase && wr == wc) {
        #pragma unroll
        for (int mi = 0; mi < 4; ++mi)
            #pragma unroll
            for (int ni = 0; ni < 4; ++ni)
                #pragma unroll
                for (int j = 0; j < 4; ++j) {
                    const int rr = wr*64 + mi*16 + (l >> 4)*4 + j;
                    const int cc = wc*64 + ni*16 + lr;
                    if (rr == cc)
                        diagv[(size_t)n * LLEN + rowBase + rr] = acc[mi][ni][j];
                }
    }
}

// ---- X f32 -> Xb bf16 + Xb8 fp8, single pass ----
__global__ __launch_bounds__(256) void cast_x_dual(
    const float* __restrict__ in, unsigned short* __restrict__ outb,
    unsigned char* __restrict__ out8, int n8)
{
    int i = blockIdx.x * 256 + threadIdx.x;
    if (i >= n8) return;
    const float4* p = reinterpret_cast<const float4*>(in) + (size_t)i * 2;
    float4 a = p[0], b = p[1];
    short8 o;
    o[0] = (short)f2bf(a.x); o[1] = (short)f2bf(a.y);
    o[2] = (short)f2bf(a.z); o[3] = (short)f2bf(a.w);
    o[4] = (short)f2bf(b.x); o[5] = (short)f2bf(b.y);
    o[6] = (short)f2bf(b.z); o[7] = (short)f2bf(b.w);
    unsigned w0 = pack4_fp8(a.x, a.y, a.z, a.w);
    unsigned w1 = pack4_fp8(b.x, b.y, b.z, b.w);
    *(reinterpret_cast<short8*>(outb) + i) = o;
    uint2 pk; pk.x = w0; pk.y = w1;
    *(reinterpret_cast<uint2*>(out8) + i) = pk;
}

// ---- Wq,Wk f32 -> bf16 (blockIdx.y selects) ----
__global__ __launch_bounds__(256) void cast_w2(
    const float* __restrict__ W0, const float* __restrict__ W1,
    unsigned short* __restrict__ out0, unsigned short* __restrict__ out1, int n8)
{
    int i = blockIdx.x * 256 + threadIdx.x;
    if (i >= n8) return;
    const float* in = blockIdx.y ? W1 : W0;
    unsigned short* outp = blockIdx.y ? out1 : out0;
    const float4* p = reinterpret_cast<const float4*>(in) + (size_t)i * 2;
    float4 a = p[0], b = p[1];
    short8 o;
    o[0] = (short)f2bf(a.x); o[1] = (short)f2bf(a.y);
    o[2] = (short)f2bf(a.z); o[3] = (short)f2bf(a.w);
    o[4] = (short)f2bf(b.x); o[5] = (short)f2bf(b.y);
    o[6] = (short)f2bf(b.z); o[7] = (short)f2bf(b.w);
    *(reinterpret_cast<short8*>(outp) + i) = o;
}

// ---- W (K x N fp32) -> bf16 N x K ----
__global__ __launch_bounds__(256) void transpose_cast_bf16(
    const float* __restrict__ W, unsigned short* __restrict__ Wt)
{
    __shared__ float tile[32][33];
    const int tx = threadIdx.x & 31, ty = threadIdx.x >> 5;
    const int c0 = blockIdx.x * 32, r0 = blockIdx.y * 32;
    #pragma unroll
    for (int r = 0; r < 4; ++r)
        tile[ty + r*8][tx] = W[(size_t)(r0 + ty + r*8) * HDIM + c0 + tx];
    __syncthreads();
    #pragma unroll
    for (int r = 0; r < 4; ++r)
        Wt[(size_t)(c0 + ty + r*8) * HDIM + r0 + tx] = f2bf(tile[tx][ty + r*8]);
}

// ---- W (K x N fp32) -> fp8 N x K, value scaled ----
__global__ __launch_bounds__(256) void transpose_cast_fp8(
    const float* __restrict__ W, unsigned char* __restrict__ Wt, float scale)
{
    __shared__ float tile[32][33];
    const int tx = threadIdx.x & 31, ty = threadIdx.x >> 5;
    const int c0 = blockIdx.x * 32, r0 = blockIdx.y * 32;
    #pragma unroll
    for (int r = 0; r < 4; ++r)
        tile[ty + r*8][tx] = W[(size_t)(r0 + ty + r*8) * HDIM + c0 + tx];
    __syncthreads();
    #pragma unroll
    for (int r = 0; r < 4; ++r)
        Wt[(size_t)(c0 + ty + r*8) * HDIM + r0 + tx] = f2fp8(tile[tx][ty + r*8] * scale);
}

// ---- p[i] = Wq[i,:] . bk ----
__global__ __launch_bounds__(256) void pvec_kernel(
    const float* __restrict__ Wq, const float* __restrict__ bk,
    float* __restrict__ p)
{
    const int row = blockIdx.x * 4 + (threadIdx.x >> 6);
    const int l = threadIdx.x & 63;
    float s = 0.f;
    #pragma unroll
    for (int c = 0; c < HDIM; c += 64)
        s += Wq[(size_t)row * HDIM + c + l] * bk[c + l];
    #pragma unroll
    for (int off = 32; off > 0; off >>= 1) s += __shfl_down(s, off);
    if (l == 0) p[row] = s;
}

// ---- u[a] = sc2 * Xb[a,:] . p ----
__global__ __launch_bounds__(256) void uvec_kernel(
    const unsigned short* __restrict__ Xb, const float* __restrict__ p,
    float* __restrict__ u, float sc2)
{
    const int row = blockIdx.x * 4 + (threadIdx.x >> 6);
    const int l = threadIdx.x & 63;
    const unsigned short* xr = Xb + (size_t)row * HDIM + l * 16;
    float s = 0.f;
    #pragma unroll
    for (int k = 0; k < 2; ++k) {
        short8 v = *reinterpret_cast<const short8*>(xr + k*8);
        #pragma unroll
        for (int j = 0; j < 8; ++j)
            s += bf2f((unsigned short)v[j]) * p[l*16 + k*8 + j];
    }
    #pragma unroll
    for (int off = 32; off > 0; off >>= 1) s += __shfl_down(s, off);
    if (l == 0) u[row] = s * sc2;
}

// ---- h1 = bf16( LN(diag*V8 + Xb) * g1 + b1 ) ----
__global__ __launch_bounds__(256) void ln1_kernel(
    const unsigned char* __restrict__ V8, const unsigned short* __restrict__ Xbp,
    const float* __restrict__ colsum, const float* __restrict__ diagval,
    const float* __restrict__ uvec,
    const float* __restrict__ g1, const float* __restrict__ b1,
    unsigned short* __restrict__ h1)
{
    const int row = blockIdx.x;
    const size_t base = (size_t)row * HDIM;
    const float dv = __expf(diagval[row] + uvec[row]) / colsum[row];
    const int h0 = threadIdx.x * 4;

    unsigned vv = *reinterpret_cast<const unsigned*>(&V8[base + h0]);
    ushort4v xx = *reinterpret_cast<const ushort4v*>(&Xbp[base + h0]);
    float y[4];
    y[0] = dv * fp8d((unsigned char)(vv      )) + bf2f(xx[0]);
    y[1] = dv * fp8d((unsigned char)(vv >>  8)) + bf2f(xx[1]);
    y[2] = dv * fp8d((unsigned char)(vv >> 16)) + bf2f(xx[2]);
    y[3] = dv * fp8d((unsigned char)(vv >> 24)) + bf2f(xx[3]);

    float s = y[0]+y[1]+y[2]+y[3];
    float s2 = y[0]*y[0]+y[1]*y[1]+y[2]*y[2]+y[3]*y[3];
    #pragma unroll
    for (int off = 32; off > 0; off >>= 1) {
        s  += __shfl_down(s,  off);
        s2 += __shfl_down(s2, off);
    }
    __shared__ float ws1[4], ws2[4];
    const int wid = threadIdx.x >> 6;
    if ((threadIdx.x & 63) == 0) { ws1[wid] = s; ws2[wid] = s2; }
    __syncthreads();
    const float S  = ws1[0]+ws1[1]+ws1[2]+ws1[3];
    const float S2 = ws2[0]+ws2[1]+ws2[2]+ws2[3];
    const float m   = S  * (1.0f / HDIM);
    const float var = S2 * (1.0f / HDIM) - m*m;
    const float inv = rsqrtf(var + LNEPS);

    float4 gg = *reinterpret_cast<const float4*>(&g1[h0]);
    float4 bb = *reinterpret_cast<const float4*>(&b1[h0]);
    ushort4v o;
    o[0] = f2bf((y[0]-m)*inv*gg.x + bb.x);
    o[1] = f2bf((y[1]-m)*inv*gg.y + bb.y);
    o[2] = f2bf((y[2]-m)*inv*gg.z + bb.z);
    o[3] = f2bf((y[3]-m)*inv*gg.w + bb.w);
    *reinterpret_cast<ushort4v*>(&h1[base + h0]) = o;
}

// ---- out = fp32( LN(Y) * g2 + b2 ), Y = G + h1 prefused in FF epilogue ----
__global__ __launch_bounds__(256) void ln2_kernel(
    const unsigned short* __restrict__ Yb,
    const float* __restrict__ g2, const float* __restrict__ b2,
    float* __restrict__ out)
{
    const int row = blockIdx.x;
    const size_t base = (size_t)row * HDIM;
    const int h0 = threadIdx.x * 4;

    ushort4v yv = *reinterpret_cast<const ushort4v*>(&Yb[base + h0]);
    float y[4];
    y[0] = bf2f(yv[0]); y[1] = bf2f(yv[1]); y[2] = bf2f(yv[2]); y[3] = bf2f(yv[3]);

    float s = y[0]+y[1]+y[2]+y[3];
    float s2 = y[0]*y[0]+y[1]*y[1]+y[2]*y[2]+y[3]*y[3];
    #pragma unroll
    for (int off = 32; off > 0; off >>= 1) {
        s  += __shfl_down(s,  off);
        s2 += __shfl_down(s2, off);
    }
    __shared__ float ws1[4], ws2[4];
    const int wid = threadIdx.x >> 6;
    if ((threadIdx.x & 63) == 0) { ws1[wid] = s; ws2[wid] = s2; }
    __syncthreads();
    const float S  = ws1[0]+ws1[1]+ws1[2]+ws1[3];
    const float S2 = ws2[0]+ws2[1]+ws2[2]+ws2[3];
    const float m   = S  * (1.0f / HDIM);
    const float var = S2 * (1.0f / HDIM) - m*m;
    const float inv = rsqrtf(var + LNEPS);

    float4 gg = *reinterpret_cast<const float4*>(&g2[h0]);
    float4 bb = *reinterpret_cast<const float4*>(&b2[h0]);
    float4 o;
    o.x = (y[0]-m)*inv*gg.x + bb.x;
    o.y = (y[1]-m)*inv*gg.y + bb.y;
    o.z = (y[2]-m)*inv*gg.z + bb.z;
    o.w = (y[3]-m)*inv*gg.w + bb.w;
    *reinterpret_cast<float4*>(&out[base + h0]) = o;
}

extern "C" void kernel_launch(void* const* d_in, const int* in_sizes, int n_in,
                              void* d_out, int out_size, void* d_ws, size_t ws_size,
                              hipStream_t stream) {
    (void)in_sizes; (void)n_in; (void)out_size; (void)ws_size;
    const float* X  = (const float*)d_in[0];
    const float* Wq = (const float*)d_in[1];
    const float* bq = (const float*)d_in[2];   (void)bq; // cancels in diag/colsum ratio
    const float* Wk = (const float*)d_in[3];
    const float* bk = (const float*)d_in[4];
    const float* Wv = (const float*)d_in[5];
    const float* bv = (const float*)d_in[6];
    const float* Wf = (const float*)d_in[7];
    const float* bf = (const float*)d_in[8];
    const float* g1 = (const float*)d_in[9];
    const float* b1 = (const float*)d_in[10];
    const float* g2 = (const float*)d_in[11];
    const float* b2 = (const float*)d_in[12];
    float* out = (float*)d_out;

    const size_t MATE = (size_t)NB * LLEN * HDIM;   // 16,777,216 elements
    const size_t WE   = (size_t)HDIM * HDIM;

    // d_out staging: Xb bf16 [0,32MiB), V8 fp8 [32,48MiB). Dead before ln2 writes out.
    unsigned short* Xb  = (unsigned short*)d_out;
    unsigned char*  V8  = (unsigned char*)(Xb + MATE);

    unsigned short* h1b   = (unsigned short*)d_ws;      // 32 MiB
    unsigned short* Yb    = h1b + MATE;                 // 32 MiB (G + h1, FF output)
    unsigned short* WfT   = Yb + MATE;                  // 2 MiB
    unsigned short* Wqb   = WfT + WE;                   // 2 MiB
    unsigned short* Wkb   = Wqb + WE;                   // 2 MiB
    unsigned char*  Wqk8T = (unsigned char*)(Wkb + WE); // 1 MiB; [Wqk8T|Wv8T] contiguous
    unsigned char*  Wv8T  = Wqk8T + WE;                 // 1 MiB
    // colsum..zvec: one contiguous memset region (diagv/pv/uv fully overwritten later)
    float* colsum = (float*)(Wv8T + WE);                // 64 KiB
    float* diagv  = colsum + (size_t)NB * LLEN;         // 64 KiB
    float* pv     = diagv + (size_t)NB * LLEN;          // 4 KiB
    float* uv     = pv + HDIM;                          // 64 KiB
    float* zvec   = uv + (size_t)NB * LLEN;             // 4 KiB
    unsigned char* Xq8 = (unsigned char*)(zvec + HDIM); // 16 MiB
    unsigned char* Xb8 = Xq8 + MATE;                    // 16 MiB
    float* wqkSlabs = (float*)(Xb8 + MATE);             // 16 MiB (4 x f32 1024^2)

    const int M = NB * LLEN;            // 16384
    const float sc2 = 1.0f / 1024.0f;   // (1/sqrt(H))^2

    const size_t mset = (3*(size_t)NB*LLEN + 2*HDIM) * sizeof(float);
    hipMemsetAsync(colsum, 0, mset, stream);

    cast_x_dual<<<(int)(MATE/8) / 256, 256, 0, stream>>>(X, Xb, Xb8, (int)(MATE/8));
    {
        dim3 cg((int)(WE/8) / 256, 2);
        cast_w2<<<cg, 256, 0, stream>>>(Wq, Wk, Wqb, Wkb, (int)(WE/8));
    }
    {
        dim3 tgrid(HDIM / 32, HDIM / 32);
        transpose_cast_bf16<<<tgrid, 256, 0, stream>>>(Wf, WfT);
        transpose_cast_fp8<<<tgrid, 256, 0, stream>>>(Wv, Wv8T, 16.0f);   // x2^4
    }

    // Wqk split-K (128^2): 256 blocks -> f32 slabs -> x64 fp8
    gemm_wqk_splitk<<<256, NTHR, 0, stream>>>(Wkb, Wqb, wqkSlabs);
    wqk_reduce_cast<<<(int)(WE/4) / 256, 256, 0, stream>>>(wqkSlabs, Wqk8T);

    // u'[a] = sc2 * X[a,:].(Wq @ bk)
    pvec_kernel<<<HDIM / 4, 256, 0, stream>>>(Wq, bk, pv);
    uvec_kernel<<<M / 4, 256, 0, stream>>>(Xb, pv, uv, sc2);

    // fp8 fused proj (128^2): [Xq8 | V8] = Xb8 @ [Wqk8T | Wv8T]^T
    // mat0: sb=2^-16 (Wqk x2^16 = x64/sc2), epilogue x1024 -> Xq8 (qk sa=2^-10 undoes)
    // mat1: sb=2^-4  (Wv  x2^4),            epilogue +bv   -> V8
    {
        const int gx = 2 * HDIM / BM;       // 16
        const int nwg = gx * (M / BM);      // 2048 (%8==0)
        gemm_proj_fp8<<<nwg, NTHR, 0, stream>>>(Xb8, Wqk8T, zvec, bv,
                                                Xq8, V8, 1024.0f, 1.0f,
                                                0x6F6F6F6Fu /*2^-16*/,
                                                0x7B7B7B7Bu /*2^-4*/, gx);
    }

    // qk (128^2): 2048 blocks, bid&7 = batch -> per-XCD L2 residency
    qk_colsum_diag_fp8<<<2048, NTHR, 0, stream>>>(Xq8, Xb8, uv, colsum, diagv);

    ln1_kernel<<<M, 256, 0, stream>>>(V8, Xb, colsum, diagv, uv, g1, b1, h1b);

    // FF GEMM (bf16, 256^2) with fused residual: Yb = G + bf + h1
    {
        const int gx = HDIM / BM2;          // 4
        const int nwg = gx * (M / BM2);     // 256
        gemm_ff<<<nwg, NTHR2, 0, stream>>>(h1b, WfT, bf, h1b, Yb, gx);
    }

    ln2_kernel<<<M, 256, 0, stream>>>(Yb, g2, b2, out);
}

// Round 19
// 208.904 us; speedup vs baseline: 1.1657x; 1.1657x over previous
//
#include <hip/hip_runtime.h>
#include <math.h>

#define NB   8
#define LLEN 2048
#define HDIM 1024
#define LNEPS 1e-5f

#define BM 128               // 128^2 tiles for fp8 kernels (2 blocks/CU)
#define BK 64                // bf16 K-tile (elems); fp8 K-tile = 128 (bytes)
#define NT_K (HDIM / BK)     // 16 bf16 K-tiles
#define NT_K8 (HDIM / 128)   // 8 fp8 K-tiles
#define NTHR 256             // 4 waves (128^2 kernels)
#define TB 16384             // 128^2 tile bytes: 128 rows x 128 B

#define BM2 256              // 256^2 tile for bf16 FF (1 block/CU, 8 waves)
#define NTHR2 512
#define SLOT2 (BM2 * BK)     // 32 KiB per 256^2 operand slot

typedef __attribute__((ext_vector_type(8))) short short8;
typedef __attribute__((ext_vector_type(4))) unsigned short ushort4v;
typedef __attribute__((ext_vector_type(4))) float f32x4;
typedef __attribute__((ext_vector_type(4))) int int4v;
typedef __attribute__((ext_vector_type(8))) int int8v;
typedef __attribute__((ext_vector_type(8))) unsigned char uchar8;

typedef __attribute__((address_space(3))) void lds_void;
typedef const __attribute__((address_space(1))) void glob_void;

__device__ __forceinline__ unsigned short f2bf(float f) {
    union { float f; unsigned u; } v; v.f = f;
    unsigned r = v.u + 0x7FFFu + ((v.u >> 16) & 1u);
    return (unsigned short)(r >> 16);
}
__device__ __forceinline__ float bf2f(unsigned short h) {
    union { unsigned u; float f; } v; v.u = ((unsigned)h) << 16;
    return v.f;
}

// OCP e4m3fn encode, RNE (HW-verified rounds 8-16). Fallback path.
__device__ __forceinline__ unsigned char f2fp8(float x) {
    union { float f; unsigned u; } v; v.f = x;
    unsigned s = (v.u >> 24) & 0x80u;
    float a = fabsf(x);
    if (!(a < 448.f)) return (unsigned char)(s | 0x7E);
    int e = (int)((v.u >> 23) & 0xFF) - 127;
    if (e < -6) e = -6;
    float q = rintf(ldexpf(a, 3 - e));
    if (q >= 16.f) { q *= 0.5f; e += 1; }
    int qi = (int)q;
    unsigned byte = (qi < 8) ? (unsigned)qi
                             : (((unsigned)(e + 7) << 3) | (unsigned)(qi - 8));
    return (unsigned char)(s | byte);
}
// e4m3fn decode (cold path, 4/thread in ln1)
__device__ __forceinline__ float fp8d(unsigned char b) {
    int e = (b >> 3) & 15, m = b & 7;
    float v = e ? ldexpf((float)(8 + m), e - 10) : ldexpf((float)m, -9);
    return (b & 0x80) ? -v : v;
}

// Pack 4 f32 -> 4 fp8 bytes (HW v_cvt_pk_fp8_f32 when available).
__device__ __forceinline__ unsigned pack4_fp8(float a, float b, float c, float d) {
#if __has_builtin(__builtin_amdgcn_cvt_pk_fp8_f32)
    int r = __builtin_amdgcn_cvt_pk_fp8_f32(a, b, 0, false);
    r = __builtin_amdgcn_cvt_pk_fp8_f32(c, d, r, true);
    return (unsigned)r;
#else
    return (unsigned)f2fp8(a) | ((unsigned)f2fp8(b) << 8)
         | ((unsigned)f2fp8(c) << 16) | ((unsigned)f2fp8(d) << 24);
#endif
}

__device__ __forceinline__ void wg_barrier() {
    asm volatile("" ::: "memory");
    __builtin_amdgcn_s_barrier();
    asm volatile("" ::: "memory");
}

// ================= 128^2 pipelines (fp8 qk/proj + wqk splitk) =================
// XOR swizzle byte(r,cb) = r*128 + (cb ^ ((r&7)<<4)); pre-applied to the
// per-lane GLOBAL source (rule 21), LDS dest linear.
__device__ __forceinline__ void stage128_bf16(
    const unsigned short* __restrict__ src, int R0, int kcol0,
    unsigned short* ldsDst, int w, int l)
{
    const int rsub = l >> 3;
    const int ce = 8 * ((l & 7) ^ rsub);
    #pragma unroll
    for (int s = 0; s < 4; ++s) {
        const int r = s*32 + w*8 + rsub;
        __builtin_amdgcn_global_load_lds(
            (glob_void*)(src + (size_t)(R0 + r) * HDIM + kcol0 + ce),
            (lds_void*)(ldsDst + s*2048 + w*512), 16, 0, 0);
    }
}

__device__ __forceinline__ void stage128_fp8(
    const unsigned char* __restrict__ src, int R0, int kcol0,
    unsigned char* ldsDst, int w, int l)
{
    const int rsub = l >> 3;
    const int cb = ((l & 7) ^ rsub) << 4;
    #pragma unroll
    for (int s = 0; s < 4; ++s) {
        const int r = s*32 + w*8 + rsub;
        __builtin_amdgcn_global_load_lds(
            (glob_void*)(src + (size_t)(R0 + r) * HDIM + kcol0 + cb),
            (lds_void*)(ldsDst + s*4096 + w*1024), 16, 0, 0);
    }
}

__device__ __forceinline__ void pipe128_bf16(
    const unsigned short* __restrict__ srcA,
    const unsigned short* __restrict__ srcB,
    int rowBase, int colBase, int k0, int nt,
    unsigned short* lds, f32x4 (&acc)[4][4])
{
    const int t = threadIdx.x, w = t >> 6, l = t & 63;
    const int wr = w >> 1, wc = w & 1;
    const int lr = l & 15;
    const int sw = (l & 7) << 4;
    const int aRB = (wr*64 + lr) * 128;
    const int bRB = (wc*64 + lr) * 128;
    const int c0 = ((l >> 4) * 16) ^ sw;
    const int c1 = (64 + ((l >> 4) * 16)) ^ sw;

    unsigned short* sA[2] = { lds,          lds + 2*(TB/2) };
    unsigned short* sB[2] = { lds + TB/2,   lds + 3*(TB/2) };

    stage128_bf16(srcA, rowBase, k0,      sA[0], w, l);
    stage128_bf16(srcB, colBase, k0,      sB[0], w, l);
    stage128_bf16(srcA, rowBase, k0 + BK, sA[1], w, l);
    stage128_bf16(srcB, colBase, k0 + BK, sB[1], w, l);
    asm volatile("s_waitcnt vmcnt(8)" ::: "memory");
    wg_barrier();

    for (int kt = 0; kt < nt; ++kt) {
        const char* bufA = (const char*)sA[kt & 1];
        const char* bufB = (const char*)sB[kt & 1];
        #pragma unroll
        for (int kk = 0; kk < 2; ++kk) {
            const int cc = kk ? c1 : c0;
            short8 af[4], bfr[4];
            #pragma unroll
            for (int mi = 0; mi < 4; ++mi)
                af[mi] = *(const short8*)(bufA + aRB + mi*2048 + cc);
            #pragma unroll
            for (int ni = 0; ni < 4; ++ni)
                bfr[ni] = *(const short8*)(bufB + bRB + ni*2048 + cc);
            #pragma unroll
            for (int mi = 0; mi < 4; ++mi)
                #pragma unroll
                for (int ni = 0; ni < 4; ++ni)
                    acc[mi][ni] = __builtin_amdgcn_mfma_f32_16x16x32_bf16(
                        af[mi], bfr[ni], acc[mi][ni], 0, 0, 0);
        }
        if (kt == nt - 1) break;
        wg_barrier();
        if (kt + 2 < nt) {
            stage128_bf16(srcA, rowBase, k0 + (kt+2)*BK, sA[kt&1], w, l);
            stage128_bf16(srcB, colBase, k0 + (kt+2)*BK, sB[kt&1], w, l);
            asm volatile("s_waitcnt vmcnt(8)" ::: "memory");
        } else {
            asm volatile("s_waitcnt vmcnt(0)" ::: "memory");
        }
        wg_barrier();
    }
}

__device__ __forceinline__ void pipe128_fp8(
    const unsigned char* __restrict__ srcA,
    const unsigned char* __restrict__ srcB,
    int rowBase, int colBase,
    unsigned char* lds, f32x4 (&acc)[4][4],
    unsigned sa, unsigned sb)
{
    const int t = threadIdx.x, w = t >> 6, l = t & 63;
    const int wr = w >> 1, wc = w & 1;
    const int lr = l & 15;
    const int sw = (l & 7) << 4;
    const int aRB = (wr*64 + lr) * 128;
    const int bRB = (wc*64 + lr) * 128;
    const int g0 = (l >> 4) * 32;
    const int cc0 = g0 ^ sw;
    const int cc1 = (g0 + 16) ^ sw;

    unsigned char* sA[2] = { lds,        lds + 2*TB };
    unsigned char* sB[2] = { lds + TB,   lds + 3*TB };

    stage128_fp8(srcA, rowBase, 0,   sA[0], w, l);
    stage128_fp8(srcB, colBase, 0,   sB[0], w, l);
    stage128_fp8(srcA, rowBase, 128, sA[1], w, l);
    stage128_fp8(srcB, colBase, 128, sB[1], w, l);
    asm volatile("s_waitcnt vmcnt(8)" ::: "memory");
    wg_barrier();

    for (int kt = 0; kt < NT_K8; ++kt) {
        const char* bufA = (const char*)sA[kt & 1];
        const char* bufB = (const char*)sB[kt & 1];
        int8v b8[4];
        #pragma unroll
        for (int ni = 0; ni < 4; ++ni)
            b8[ni] = __builtin_shufflevector(
                *(const int4v*)(bufB + bRB + ni*2048 + cc0),
                *(const int4v*)(bufB + bRB + ni*2048 + cc1),
                0, 1, 2, 3, 4, 5, 6, 7);
        #pragma unroll
        for (int mi = 0; mi < 4; ++mi) {
            int8v a8 = __builtin_shufflevector(
                *(const int4v*)(bufA + aRB + mi*2048 + cc0),
                *(const int4v*)(bufA + aRB + mi*2048 + cc1),
                0, 1, 2, 3, 4, 5, 6, 7);
            #pragma unroll
            for (int ni = 0; ni < 4; ++ni)
                acc[mi][ni] = __builtin_amdgcn_mfma_scale_f32_16x16x128_f8f6f4(
                    a8, b8[ni], acc[mi][ni], 0, 0, 0, sa, 0, sb);
        }
        if (kt == NT_K8 - 1) break;
        wg_barrier();
        if (kt + 2 < NT_K8) {
            stage128_fp8(srcA, rowBase, (kt+2)*128, sA[kt&1], w, l);
            stage128_fp8(srcB, colBase, (kt+2)*128, sB[kt&1], w, l);
            asm volatile("s_waitcnt vmcnt(8)" ::: "memory");
        } else {
            asm volatile("s_waitcnt vmcnt(0)" ::: "memory");
        }
        wg_barrier();
    }
}

// ================= 256^2 bf16 pipeline (FF only; round-14/16 proven) =================
__device__ __forceinline__ void stage256_bf16(
    const unsigned short* __restrict__ src, int R0, int kcol0,
    unsigned short* ldsDst, int w, int lane)
{
    const int rsub = lane >> 3;
    const int csw  = 8 * ((lane & 7) ^ rsub);
    #pragma unroll
    for (int s = 0; s < 4; ++s) {
        const int r = (s*8 + w)*8 + rsub;
        __builtin_amdgcn_global_load_lds(
            (glob_void*)(src + (size_t)(R0 + r) * HDIM + kcol0 + csw),
            (lds_void*)(ldsDst + (s*8 + w)*512), 16, 0, 0);
    }
}

__device__ __forceinline__ void pipe256_bf16(
    const unsigned short* __restrict__ srcA,
    const unsigned short* __restrict__ srcB,
    int rowBase, int colBase,
    unsigned short* lds, f32x4 (&acc)[8][4])
{
    const int t = threadIdx.x, w = t >> 6, l = t & 63;
    const int wr = w >> 2, wc = w & 3;
    const int lr = l & 15;
    const int sw = (l & 7) << 4;
    const int aRB = (wr*128 + lr) * 128;
    const int bRB = (wc*64  + lr) * 128;
    const int c0 = ((l >> 4) * 16) ^ sw;
    const int c1 = (64 + ((l >> 4) * 16)) ^ sw;

    unsigned short* sA[2] = { lds,            lds + 2*SLOT2 };
    unsigned short* sB[2] = { lds + SLOT2,    lds + 3*SLOT2 };

    stage256_bf16(srcA, rowBase, 0,  sA[0], w, l);
    stage256_bf16(srcB, colBase, 0,  sB[0], w, l);
    stage256_bf16(srcA, rowBase, BK, sA[1], w, l);
    stage256_bf16(srcB, colBase, BK, sB[1], w, l);
    asm volatile("s_waitcnt vmcnt(8)" ::: "memory");
    wg_barrier();

    for (int kt = 0; kt < NT_K; ++kt) {
        const char* bufA = (const char*)sA[kt & 1];
        const char* bufB = (const char*)sB[kt & 1];
        #pragma unroll
        for (int kk = 0; kk < 2; ++kk) {
            const int cc = kk ? c1 : c0;
            short8 af[8], bfr[4];
            #pragma unroll
            for (int mi = 0; mi < 8; ++mi)
                af[mi] = *(const short8*)(bufA + aRB + mi*2048 + cc);
            #pragma unroll
            for (int ni = 0; ni < 4; ++ni)
                bfr[ni] = *(const short8*)(bufB + bRB + ni*2048 + cc);
            #pragma unroll
            for (int mi = 0; mi < 8; ++mi)
                #pragma unroll
                for (int ni = 0; ni < 4; ++ni)
                    acc[mi][ni] = __builtin_amdgcn_mfma_f32_16x16x32_bf16(
                        af[mi], bfr[ni], acc[mi][ni], 0, 0, 0);
        }
        if (kt == NT_K - 1) break;
        wg_barrier();
        if (kt + 2 < NT_K) {
            stage256_bf16(srcA, rowBase, (kt+2)*BK, sA[kt&1], w, l);
            stage256_bf16(srcB, colBase, (kt+2)*BK, sB[kt&1], w, l);
            asm volatile("s_waitcnt vmcnt(8)" ::: "memory");
        } else {
            asm volatile("s_waitcnt vmcnt(0)" ::: "memory");
        }
        wg_barrier();
    }
}

// ---- FF GEMM (bf16, 256^2): C = bf16(A @ Bt^T + bias) ----
__global__ __launch_bounds__(NTHR2, 2) void gemm_ff(
    const unsigned short* __restrict__ A,
    const unsigned short* __restrict__ Bt,
    const float* __restrict__ bias,
    unsigned short* __restrict__ C, int gx)
{
    __shared__ __align__(16) unsigned short lds[4 * SLOT2];   // 128 KiB
    const int nwg = gridDim.x, bid = blockIdx.x;
    const int swz = (bid & 7) * (nwg >> 3) + (bid >> 3);
    const int bx = swz % gx, by = swz / gx;
    const int rowBase = by * BM2, colBase = bx * BM2;

    f32x4 acc[8][4] = {};
    pipe256_bf16(A, Bt, rowBase, colBase, lds, acc);

    const int t = threadIdx.x, w = t >> 6, l = t & 63;
    const int wr = w >> 2, wc = w & 3;
    const int lr = l & 15;

    #pragma unroll
    for (int ni = 0; ni < 4; ++ni) {
        const int col = colBase + wc*64 + ni*16 + lr;
        const float bv = bias[col];
        #pragma unroll
        for (int mi = 0; mi < 8; ++mi) {
            const int row0 = rowBase + wr*128 + mi*16 + (l >> 4) * 4;
            #pragma unroll
            for (int j = 0; j < 4; ++j)
                C[(size_t)(row0 + j) * HDIM + col] = f2bf(acc[mi][ni][j] + bv);
        }
    }
}

// ---- Wqk split-K (128^2): 64 tiles x 4 K-slices; f32 partial slabs ----
__global__ __launch_bounds__(NTHR) void gemm_wqk_splitk(
    const unsigned short* __restrict__ Wkb,
    const unsigned short* __restrict__ Wqb,
    float* __restrict__ slabs)
{
    __shared__ __align__(16) unsigned short lds[2 * TB];
    const int bid = blockIdx.x;      // 256
    const int kz = bid & 3, tile = bid >> 2;
    const int rowBase = (tile >> 3) * BM, colBase = (tile & 7) * BM;

    f32x4 acc[4][4] = {};
    pipe128_bf16(Wkb, Wqb, rowBase, colBase, kz * (HDIM/4), NT_K/4, lds, acc);

    float* out = slabs + (size_t)kz * HDIM * HDIM;
    const int t = threadIdx.x, w = t >> 6, l = t & 63;
    const int wr = w >> 1, wc = w & 1;
    const int lr = l & 15;

    #pragma unroll
    for (int ni = 0; ni < 4; ++ni) {
        const int col = colBase + wc*64 + ni*16 + lr;
        #pragma unroll
        for (int mi = 0; mi < 4; ++mi) {
            const int row0 = rowBase + wr*64 + mi*16 + (l >> 4) * 4;
            #pragma unroll
            for (int j = 0; j < 4; ++j)
                out[(size_t)(row0 + j) * HDIM + col] = acc[mi][ni][j];
        }
    }
}

// ---- sum 4 slabs, scale x64, write fp8 ----
__global__ __launch_bounds__(256) void wqk_reduce_cast(
    const float* __restrict__ slabs, unsigned char* __restrict__ out8)
{
    const size_t WEl = (size_t)HDIM * HDIM;
    const size_t i = ((size_t)blockIdx.x * 256 + threadIdx.x) * 4;
    float4 a = *reinterpret_cast<const float4*>(slabs + i);
    float4 b = *reinterpret_cast<const float4*>(slabs + WEl + i);
    float4 c = *reinterpret_cast<const float4*>(slabs + 2*WEl + i);
    float4 d = *reinterpret_cast<const float4*>(slabs + 3*WEl + i);
    unsigned wd = pack4_fp8(64.f*(a.x+b.x+c.x+d.x), 64.f*(a.y+b.y+c.y+d.y),
                            64.f*(a.z+b.z+c.z+d.z), 64.f*(a.w+b.w+c.w+d.w));
    *reinterpret_cast<unsigned*>(out8 + i) = wd;
}

// ---- fp8 fused proj (128^2): [Xq8 | V8] = fp8( al * (Xb8 @ W8^T + bias) ) ----
__global__ __launch_bounds__(NTHR) void gemm_proj_fp8(
    const unsigned char* __restrict__ A,
    const unsigned char* __restrict__ Bt,
    const float* __restrict__ bias0, const float* __restrict__ bias1,
    unsigned char* __restrict__ C0, unsigned char* __restrict__ C1,
    float al0, float al1, unsigned sb0, unsigned sb1, int gx)
{
    __shared__ __align__(16) unsigned char lds8[4 * TB];
    const int nwg = gridDim.x, bid = blockIdx.x;
    const int swz = (bid & 7) * (nwg >> 3) + (bid >> 3);
    const int bx = swz % gx, by = swz / gx;
    const int rowBase = by * BM, colBase = bx * BM;

    const int mat = colBase >> 10;

    f32x4 acc[4][4] = {};
    pipe128_fp8(A, Bt, rowBase, colBase, lds8, acc,
                0x7F7F7F7Fu, mat ? sb1 : sb0);

    const int t = threadIdx.x, w = t >> 6, l = t & 63;
    const int wr = w >> 1, wc = w & 1;
    const int lr = l & 15;

    unsigned char* Cm  = mat ? C1 : C0;
    const float* bm    = mat ? bias1 : bias0;
    const float am     = mat ? al1 : al0;
    const int lcb = colBase & (HDIM - 1);

    #pragma unroll
    for (int ni = 0; ni < 4; ++ni) {
        const int col = lcb + wc*64 + ni*16 + lr;
        const float bv = bm[col];
        #pragma unroll
        for (int mi = 0; mi < 4; ++mi) {
            const int row0 = rowBase + wr*64 + mi*16 + (l >> 4) * 4;
            const unsigned wd = pack4_fp8(
                am * (acc[mi][ni][0] + bv), am * (acc[mi][ni][1] + bv),
                am * (acc[mi][ni][2] + bv), am * (acc[mi][ni][3] + bv));
            #pragma unroll
            for (int j = 0; j < 4; ++j)
                Cm[(size_t)(row0 + j) * HDIM + col] = (unsigned char)(wd >> (8*j));
        }
    }
}

// ---- fp8 qk (128^2), batch-per-XCD grid: bid&7 = batch ----
__global__ __launch_bounds__(NTHR) void qk_colsum_diag_fp8(
    const unsigned char* __restrict__ Xq8,
    const unsigned char* __restrict__ Xb8,
    const float* __restrict__ uvec,
    float* __restrict__ colsum, float* __restrict__ diagv)
{
    __shared__ __align__(16) unsigned char lds8[4 * TB];
    const int bid = blockIdx.x;          // 2048
    const int n = bid & 7;
    const int rem = bid >> 3;            // 0..255
    const int rowBase = (rem & 15) * BM;
    const int colBase = (rem >> 4) * BM;
    const unsigned char* An = Xq8 + (size_t)n * LLEN * HDIM;
    const unsigned char* Bn = Xb8 + (size_t)n * LLEN * HDIM;

    f32x4 acc[4][4] = {};
    pipe128_fp8(An, Bn, rowBase, colBase, lds8, acc,
                0x75757575u, 0x7F7F7F7Fu);

    const int t = threadIdx.x, w = t >> 6, l = t & 63;
    const int wr = w >> 1, wc = w & 1;
    const int lr = l & 15;

    float ur[4][4];
    #pragma unroll
    for (int mi = 0; mi < 4; ++mi)
        #pragma unroll
        for (int j = 0; j < 4; ++j)
            ur[mi][j] = uvec[(size_t)n * LLEN + rowBase + wr*64 + mi*16 + (l>>4)*4 + j];

    #pragma unroll
    for (int ni = 0; ni < 4; ++ni) {
        float s = 0.f;
        #pragma unroll
        for (int mi = 0; mi < 4; ++mi)
            #pragma unroll
            for (int j = 0; j < 4; ++j)
                s += __expf(acc[mi][ni][j] + ur[mi][j]);
        s += __shfl_xor(s, 16);
        s += __shfl_xor(s, 32);
        if (l < 16)
            atomicAdd(&colsum[(size_t)n * LLEN + colBase + wc*64 + ni*16 + l], s);
    }

    if (rowBase == colBase && wr == wc) {
        #pragma unroll
        for (int mi = 0; mi < 4; ++mi)
            #pragma unroll
            for (int ni = 0; ni < 4; ++ni)
                #pragma unroll
                for (int j = 0; j < 4; ++j) {
                    const int rr = wr*64 + mi*16 + (l >> 4)*4 + j;
                    const int cc = wc*64 + ni*16 + lr;
                    if (rr == cc)
                        diagv[(size_t)n * LLEN + rowBase + rr] = acc[mi][ni][j];
                }
    }
}

// ---- X f32 -> Xb bf16 + Xb8 fp8, single pass ----
__global__ __launch_bounds__(256) void cast_x_dual(
    const float* __restrict__ in, unsigned short* __restrict__ outb,
    unsigned char* __restrict__ out8, int n8)
{
    int i = blockIdx.x * 256 + threadIdx.x;
    if (i >= n8) return;
    const float4* p = reinterpret_cast<const float4*>(in) + (size_t)i * 2;
    float4 a = p[0], b = p[1];
    short8 o;
    o[0] = (short)f2bf(a.x); o[1] = (short)f2bf(a.y);
    o[2] = (short)f2bf(a.z); o[3] = (short)f2bf(a.w);
    o[4] = (short)f2bf(b.x); o[5] = (short)f2bf(b.y);
    o[6] = (short)f2bf(b.z); o[7] = (short)f2bf(b.w);
    unsigned w0 = pack4_fp8(a.x, a.y, a.z, a.w);
    unsigned w1 = pack4_fp8(b.x, b.y, b.z, b.w);
    *(reinterpret_cast<short8*>(outb) + i) = o;
    uint2 pk; pk.x = w0; pk.y = w1;
    *(reinterpret_cast<uint2*>(out8) + i) = pk;
}

// ---- Wq,Wk f32 -> bf16 (blockIdx.y selects) ----
__global__ __launch_bounds__(256) void cast_w2(
    const float* __restrict__ W0, const float* __restrict__ W1,
    unsigned short* __restrict__ out0, unsigned short* __restrict__ out1, int n8)
{
    int i = blockIdx.x * 256 + threadIdx.x;
    if (i >= n8) return;
    const float* in = blockIdx.y ? W1 : W0;
    unsigned short* outp = blockIdx.y ? out1 : out0;
    const float4* p = reinterpret_cast<const float4*>(in) + (size_t)i * 2;
    float4 a = p[0], b = p[1];
    short8 o;
    o[0] = (short)f2bf(a.x); o[1] = (short)f2bf(a.y);
    o[2] = (short)f2bf(a.z); o[3] = (short)f2bf(a.w);
    o[4] = (short)f2bf(b.x); o[5] = (short)f2bf(b.y);
    o[6] = (short)f2bf(b.z); o[7] = (short)f2bf(b.w);
    *(reinterpret_cast<short8*>(outp) + i) = o;
}

// ---- W (K x N fp32) -> bf16 N x K ----
__global__ __launch_bounds__(256) void transpose_cast_bf16(
    const float* __restrict__ W, unsigned short* __restrict__ Wt)
{
    __shared__ float tile[32][33];
    const int tx = threadIdx.x & 31, ty = threadIdx.x >> 5;
    const int c0 = blockIdx.x * 32, r0 = blockIdx.y * 32;
    #pragma unroll
    for (int r = 0; r < 4; ++r)
        tile[ty + r*8][tx] = W[(size_t)(r0 + ty + r*8) * HDIM + c0 + tx];
    __syncthreads();
    #pragma unroll
    for (int r = 0; r < 4; ++r)
        Wt[(size_t)(c0 + ty + r*8) * HDIM + r0 + tx] = f2bf(tile[tx][ty + r*8]);
}

// ---- W (K x N fp32) -> fp8 N x K, value scaled ----
__global__ __launch_bounds__(256) void transpose_cast_fp8(
    const float* __restrict__ W, unsigned char* __restrict__ Wt, float scale)
{
    __shared__ float tile[32][33];
    const int tx = threadIdx.x & 31, ty = threadIdx.x >> 5;
    const int c0 = blockIdx.x * 32, r0 = blockIdx.y * 32;
    #pragma unroll
    for (int r = 0; r < 4; ++r)
        tile[ty + r*8][tx] = W[(size_t)(r0 + ty + r*8) * HDIM + c0 + tx];
    __syncthreads();
    #pragma unroll
    for (int r = 0; r < 4; ++r)
        Wt[(size_t)(c0 + ty + r*8) * HDIM + r0 + tx] = f2fp8(tile[tx][ty + r*8] * scale);
}

// ---- p[i] = Wq[i,:] . bk ----
__global__ __launch_bounds__(256) void pvec_kernel(
    const float* __restrict__ Wq, const float* __restrict__ bk,
    float* __restrict__ p)
{
    const int row = blockIdx.x * 4 + (threadIdx.x >> 6);
    const int l = threadIdx.x & 63;
    float s = 0.f;
    #pragma unroll
    for (int c = 0; c < HDIM; c += 64)
        s += Wq[(size_t)row * HDIM + c + l] * bk[c + l];
    #pragma unroll
    for (int off = 32; off > 0; off >>= 1) s += __shfl_down(s, off);
    if (l == 0) p[row] = s;
}

// ---- u[a] = sc2 * Xb[a,:] . p ----
__global__ __launch_bounds__(256) void uvec_kernel(
    const unsigned short* __restrict__ Xb, const float* __restrict__ p,
    float* __restrict__ u, float sc2)
{
    const int row = blockIdx.x * 4 + (threadIdx.x >> 6);
    const int l = threadIdx.x & 63;
    const unsigned short* xr = Xb + (size_t)row * HDIM + l * 16;
    float s = 0.f;
    #pragma unroll
    for (int k = 0; k < 2; ++k) {
        short8 v = *reinterpret_cast<const short8*>(xr + k*8);
        #pragma unroll
        for (int j = 0; j < 8; ++j)
            s += bf2f((unsigned short)v[j]) * p[l*16 + k*8 + j];
    }
    #pragma unroll
    for (int off = 32; off > 0; off >>= 1) s += __shfl_down(s, off);
    if (l == 0) u[row] = s * sc2;
}

// ---- h1 = bf16( LN(diag*V8 + Xb) * g1 + b1 ) ----
__global__ __launch_bounds__(256) void ln1_kernel(
    const unsigned char* __restrict__ V8, const unsigned short* __restrict__ Xbp,
    const float* __restrict__ colsum, const float* __restrict__ diagval,
    const float* __restrict__ uvec,
    const float* __restrict__ g1, const float* __restrict__ b1,
    unsigned short* __restrict__ h1)
{
    const int row = blockIdx.x;
    const size_t base = (size_t)row * HDIM;
    const float dv = __expf(diagval[row] + uvec[row]) / colsum[row];
    const int h0 = threadIdx.x * 4;

    unsigned vv = *reinterpret_cast<const unsigned*>(&V8[base + h0]);
    ushort4v xx = *reinterpret_cast<const ushort4v*>(&Xbp[base + h0]);
    float y[4];
    y[0] = dv * fp8d((unsigned char)(vv      )) + bf2f(xx[0]);
    y[1] = dv * fp8d((unsigned char)(vv >>  8)) + bf2f(xx[1]);
    y[2] = dv * fp8d((unsigned char)(vv >> 16)) + bf2f(xx[2]);
    y[3] = dv * fp8d((unsigned char)(vv >> 24)) + bf2f(xx[3]);

    float s = y[0]+y[1]+y[2]+y[3];
    float s2 = y[0]*y[0]+y[1]*y[1]+y[2]*y[2]+y[3]*y[3];
    #pragma unroll
    for (int off = 32; off > 0; off >>= 1) {
        s  += __shfl_down(s,  off);
        s2 += __shfl_down(s2, off);
    }
    __shared__ float ws1[4], ws2[4];
    const int wid = threadIdx.x >> 6;
    if ((threadIdx.x & 63) == 0) { ws1[wid] = s; ws2[wid] = s2; }
    __syncthreads();
    const float S  = ws1[0]+ws1[1]+ws1[2]+ws1[3];
    const float S2 = ws2[0]+ws2[1]+ws2[2]+ws2[3];
    const float m   = S  * (1.0f / HDIM);
    const float var = S2 * (1.0f / HDIM) - m*m;
    const float inv = rsqrtf(var + LNEPS);

    float4 gg = *reinterpret_cast<const float4*>(&g1[h0]);
    float4 bb = *reinterpret_cast<const float4*>(&b1[h0]);
    ushort4v o;
    o[0] = f2bf((y[0]-m)*inv*gg.x + bb.x);
    o[1] = f2bf((y[1]-m)*inv*gg.y + bb.y);
    o[2] = f2bf((y[2]-m)*inv*gg.z + bb.z);
    o[3] = f2bf((y[3]-m)*inv*gg.w + bb.w);
    *reinterpret_cast<ushort4v*>(&h1[base + h0]) = o;
}

// ---- out = fp32( LN(G + h1) * g2 + b2 ) ----
__global__ __launch_bounds__(256) void ln2_kernel(
    const unsigned short* __restrict__ Gb, const unsigned short* __restrict__ h1b,
    const float* __restrict__ g2, const float* __restrict__ b2,
    float* __restrict__ out)
{
    const int row = blockIdx.x;
    const size_t base = (size_t)row * HDIM;
    const int h0 = threadIdx.x * 4;

    ushort4v gv = *reinterpret_cast<const ushort4v*>(&Gb[base + h0]);
    ushort4v hv = *reinterpret_cast<const ushort4v*>(&h1b[base + h0]);
    float y[4];
    y[0] = bf2f(gv[0]) + bf2f(hv[0]); y[1] = bf2f(gv[1]) + bf2f(hv[1]);
    y[2] = bf2f(gv[2]) + bf2f(hv[2]); y[3] = bf2f(gv[3]) + bf2f(hv[3]);

    float s = y[0]+y[1]+y[2]+y[3];
    float s2 = y[0]*y[0]+y[1]*y[1]+y[2]*y[2]+y[3]*y[3];
    #pragma unroll
    for (int off = 32; off > 0; off >>= 1) {
        s  += __shfl_down(s,  off);
        s2 += __shfl_down(s2, off);
    }
    __shared__ float ws1[4], ws2[4];
    const int wid = threadIdx.x >> 6;
    if ((threadIdx.x & 63) == 0) { ws1[wid] = s; ws2[wid] = s2; }
    __syncthreads();
    const float S  = ws1[0]+ws1[1]+ws1[2]+ws1[3];
    const float S2 = ws2[0]+ws2[1]+ws2[2]+ws2[3];
    const float m   = S  * (1.0f / HDIM);
    const float var = S2 * (1.0f / HDIM) - m*m;
    const float inv = rsqrtf(var + LNEPS);

    float4 gg = *reinterpret_cast<const float4*>(&g2[h0]);
    float4 bb = *reinterpret_cast<const float4*>(&b2[h0]);
    float4 o;
    o.x = (y[0]-m)*inv*gg.x + bb.x;
    o.y = (y[1]-m)*inv*gg.y + bb.y;
    o.z = (y[2]-m)*inv*gg.z + bb.z;
    o.w = (y[3]-m)*inv*gg.w + bb.w;
    *reinterpret_cast<float4*>(&out[base + h0]) = o;
}

extern "C" void kernel_launch(void* const* d_in, const int* in_sizes, int n_in,
                              void* d_out, int out_size, void* d_ws, size_t ws_size,
                              hipStream_t stream) {
    (void)in_sizes; (void)n_in; (void)out_size; (void)ws_size;
    const float* X  = (const float*)d_in[0];
    const float* Wq = (const float*)d_in[1];
    const float* bq = (const float*)d_in[2];   (void)bq; // cancels in diag/colsum ratio
    const float* Wk = (const float*)d_in[3];
    const float* bk = (const float*)d_in[4];
    const float* Wv = (const float*)d_in[5];
    const float* bv = (const float*)d_in[6];
    const float* Wf = (const float*)d_in[7];
    const float* bf = (const float*)d_in[8];
    const float* g1 = (const float*)d_in[9];
    const float* b1 = (const float*)d_in[10];
    const float* g2 = (const float*)d_in[11];
    const float* b2 = (const float*)d_in[12];
    float* out = (float*)d_out;

    const size_t MATE = (size_t)NB * LLEN * HDIM;   // 16,777,216 elements
    const size_t WE   = (size_t)HDIM * HDIM;

    // d_out staging: Xb bf16 [0,32MiB), V8 fp8 [32,48MiB). Dead before ln2 writes out.
    unsigned short* Xb  = (unsigned short*)d_out;
    unsigned char*  V8  = (unsigned char*)(Xb + MATE);

    unsigned short* h1b   = (unsigned short*)d_ws;      // 32 MiB
    unsigned short* Gb    = h1b + MATE;                 // 32 MiB
    unsigned short* WfT   = Gb + MATE;                  // 2 MiB
    unsigned short* Wqb   = WfT + WE;                   // 2 MiB
    unsigned short* Wkb   = Wqb + WE;                   // 2 MiB
    unsigned char*  Wqk8T = (unsigned char*)(Wkb + WE); // 1 MiB; [Wqk8T|Wv8T] contiguous
    unsigned char*  Wv8T  = Wqk8T + WE;                 // 1 MiB
    // colsum..zvec: one contiguous memset region (diagv/pv/uv fully overwritten later)
    float* colsum = (float*)(Wv8T + WE);                // 64 KiB
    float* diagv  = colsum + (size_t)NB * LLEN;         // 64 KiB
    float* pv     = diagv + (size_t)NB * LLEN;          // 4 KiB
    float* uv     = pv + HDIM;                          // 64 KiB
    float* zvec   = uv + (size_t)NB * LLEN;             // 4 KiB
    unsigned char* Xq8 = (unsigned char*)(zvec + HDIM); // 16 MiB
    unsigned char* Xb8 = Xq8 + MATE;                    // 16 MiB
    float* wqkSlabs = (float*)(Xb8 + MATE);             // 16 MiB (4 x f32 1024^2)

    const int M = NB * LLEN;            // 16384
    const float sc2 = 1.0f / 1024.0f;   // (1/sqrt(H))^2

    const size_t mset = (3*(size_t)NB*LLEN + 2*HDIM) * sizeof(float);
    hipMemsetAsync(colsum, 0, mset, stream);

    cast_x_dual<<<(int)(MATE/8) / 256, 256, 0, stream>>>(X, Xb, Xb8, (int)(MATE/8));
    {
        dim3 cg((int)(WE/8) / 256, 2);
        cast_w2<<<cg, 256, 0, stream>>>(Wq, Wk, Wqb, Wkb, (int)(WE/8));
    }
    {
        dim3 tgrid(HDIM / 32, HDIM / 32);
        transpose_cast_bf16<<<tgrid, 256, 0, stream>>>(Wf, WfT);
        transpose_cast_fp8<<<tgrid, 256, 0, stream>>>(Wv, Wv8T, 16.0f);   // x2^4
    }

    // Wqk split-K (128^2): 256 blocks -> f32 slabs -> x64 fp8
    gemm_wqk_splitk<<<256, NTHR, 0, stream>>>(Wkb, Wqb, wqkSlabs);
    wqk_reduce_cast<<<(int)(WE/4) / 256, 256, 0, stream>>>(wqkSlabs, Wqk8T);

    // u'[a] = sc2 * X[a,:].(Wq @ bk)
    pvec_kernel<<<HDIM / 4, 256, 0, stream>>>(Wq, bk, pv);
    uvec_kernel<<<M / 4, 256, 0, stream>>>(Xb, pv, uv, sc2);

    // fp8 fused proj (128^2): [Xq8 | V8] = Xb8 @ [Wqk8T | Wv8T]^T
    // mat0: sb=2^-16 (Wqk x2^16 = x64/sc2), epilogue x1024 -> Xq8 (qk sa=2^-10 undoes)
    // mat1: sb=2^-4  (Wv  x2^4),            epilogue +bv   -> V8
    {
        const int gx = 2 * HDIM / BM;       // 16
        const int nwg = gx * (M / BM);      // 2048 (%8==0)
        gemm_proj_fp8<<<nwg, NTHR, 0, stream>>>(Xb8, Wqk8T, zvec, bv,
                                                Xq8, V8, 1024.0f, 1.0f,
                                                0x6F6F6F6Fu /*2^-16*/,
                                                0x7B7B7B7Bu /*2^-4*/, gx);
    }

    // qk (128^2): 2048 blocks, bid&7 = batch -> per-XCD L2 residency
    qk_colsum_diag_fp8<<<2048, NTHR, 0, stream>>>(Xq8, Xb8, uv, colsum, diagv);

    ln1_kernel<<<M, 256, 0, stream>>>(V8, Xb, colsum, diagv, uv, g1, b1, h1b);

    // FF GEMM (bf16, 256^2 — the faster structure for the 16-K-tile bf16 loop)
    {
        const int gx = HDIM / BM2;          // 4
        const int nwg = gx * (M / BM2);     // 256
        gemm_ff<<<nwg, NTHR2, 0, stream>>>(h1b, WfT, bf, Gb, gx);
    }

    ln2_kernel<<<M, 256, 0, stream>>>(Gb, h1b, g2, b2, out);
}